// Round 4
// baseline (12.271 us; speedup 1.0000x reference)
//
#include <hip/hip_runtime.h>

#define NF 64
#define RANK 16
// One output per 64-lane wave; 4 waves (4 outputs) per 256-thread block;
// grid = 4096 blocks for BATCH=16384.
// All per-output scalars (indices, biases, A-row) are wave-uniform -> SGPR
// s_loads. Each lane owns one feature: ue/ie are single coalesced
// global_load_dword per wave. B (4 KB) stays L1-resident. No LDS, no barrier.

__global__ __launch_bounds__(256) void MF_27436251087258_kernel(
    const int* __restrict__ users,
    const int* __restrict__ items,
    const float* __restrict__ user_emb,
    const float* __restrict__ item_emb,
    const float* __restrict__ user_bias,
    const float* __restrict__ item_bias,
    const float* __restrict__ A,
    const float* __restrict__ Bm,
    float* __restrict__ out,
    int batch)
{
    const int wave = threadIdx.x >> 6;
    const int lane = threadIdx.x & 63;
    const int i = blockIdx.x * 4 + wave;     // wave-uniform output index
    if (i >= batch) return;

    // Wave-uniform index loads -> scalar loads.
    const int u  = __builtin_amdgcn_readfirstlane(users[i]);
    const int it = __builtin_amdgcn_readfirstlane(items[i]);

    // Wave-uniform scalars: biases + full A row (64 B) -> SGPR file.
    const float ub = user_bias[u];
    const float ib = item_bias[it];
    const float* __restrict__ Arow = A + (size_t)it * RANK;

    // Per-lane feature gathers: one coalesced 256 B load per row per wave.
    const float ue = user_emb[(size_t)u  * NF + lane];
    const float ie = item_emb[(size_t)it * NF + lane];

    // corr[lane] = sum_r A[it,r] * B[r,lane]; SGPR x VGPR FMAs,
    // 4 accumulators to break the dependence chain.
    float c0 = 0.f, c1 = 0.f, c2 = 0.f, c3 = 0.f;
    #pragma unroll
    for (int r = 0; r < RANK; r += 4) {
        c0 = fmaf(Arow[r + 0], Bm[(r + 0) * NF + lane], c0);
        c1 = fmaf(Arow[r + 1], Bm[(r + 1) * NF + lane], c1);
        c2 = fmaf(Arow[r + 2], Bm[(r + 2) * NF + lane], c2);
        c3 = fmaf(Arow[r + 3], Bm[(r + 3) * NF + lane], c3);
    }
    const float corr = (c0 + c1) + (c2 + c3);

    // Per-lane partial product, then full-wave reduction (64 lanes).
    float p = ue * (ie + corr);
    p += __shfl_xor(p, 32);
    p += __shfl_xor(p, 16);
    p += __shfl_xor(p, 8);
    p += __shfl_xor(p, 4);
    p += __shfl_xor(p, 2);
    p += __shfl_xor(p, 1);

    if (lane == 0) {
        out[i] = p + ub + ib;
    }
}

extern "C" void kernel_launch(void* const* d_in, const int* in_sizes, int n_in,
                              void* d_out, int out_size, void* d_ws, size_t ws_size,
                              hipStream_t stream) {
    const int*   users     = (const int*)  d_in[0];
    const int*   items     = (const int*)  d_in[1];
    const float* user_emb  = (const float*)d_in[2];
    const float* item_emb  = (const float*)d_in[3];
    const float* user_bias = (const float*)d_in[4];
    const float* item_bias = (const float*)d_in[5];
    const float* A         = (const float*)d_in[6];
    const float* Bm        = (const float*)d_in[7];
    float* out = (float*)d_out;

    const int batch = in_sizes[0];                   // 16384
    const int outputs_per_block = 4;                 // one per wave
    const int grid = (batch + outputs_per_block - 1) / outputs_per_block;  // 4096

    MF_27436251087258_kernel<<<grid, 256, 0, stream>>>(
        users, items, user_emb, item_emb, user_bias, item_bias, A, Bm, out, batch);
}

// Round 5
// 9.869 us; speedup vs baseline: 1.2434x; 1.2434x over previous
//
#include <hip/hip_runtime.h>

#define NF 64
#define RANK 16
// R1 structure: 16 lanes per output, 16 groups per 256-thread block, 1024
// blocks (4 waves/SIMD). Changes vs R1:
//  - bias loads hoisted next to the row gathers (removes tail round trip)
//  - A row loaded as 4 broadcast float4s from global (one cache line,
//    L1-serviced) instead of 16 per-iter __shfl broadcasts
// B stays LDS-staged (R3 showed per-lane global B loads regress).

__global__ __launch_bounds__(256) void MF_27436251087258_kernel(
    const int* __restrict__ users,
    const int* __restrict__ items,
    const float* __restrict__ user_emb,
    const float* __restrict__ item_emb,
    const float* __restrict__ user_bias,
    const float* __restrict__ item_bias,
    const float* __restrict__ A,
    const float* __restrict__ Bm,
    float* __restrict__ out,
    int batch)
{
    __shared__ float Bs[RANK * NF];   // 4 KB

    const int tid = threadIdx.x;

    // Stage B [16,64] into LDS: 1024 floats, 256 threads -> one float4 each.
    {
        const float4 v = ((const float4*)Bm)[tid];
        ((float4*)Bs)[tid] = v;
    }

    const int group = tid >> 4;
    const int lane  = tid & 15;
    const int i = blockIdx.x * 16 + group;

    // ---- 1. Indices (broadcast within group).
    const int u  = users[i];
    const int it = items[i];

    // ---- 2. All random lines issued together: biases, emb rows, A row.
    const float ub = user_bias[u];
    const float ib = item_bias[it];

    const float4 ue = *(const float4*)(user_emb + (size_t)u  * NF + lane * 4);
    const float4 ie = *(const float4*)(item_emb + (size_t)it * NF + lane * 4);

    const float* Arow = A + (size_t)it * RANK;   // 64 B, one cache line
    const float4 a0 = *(const float4*)(Arow + 0);
    const float4 a1 = *(const float4*)(Arow + 4);
    const float4 a2 = *(const float4*)(Arow + 8);
    const float4 a3 = *(const float4*)(Arow + 12);

    __syncthreads();   // B staged (waits on lgkm only; gathers keep flying)

    // ---- 3. Low-rank correction: 16 x (ds_read_b128 + 4 FMA), no shuffles.
    float c0 = 0.f, c1 = 0.f, c2 = 0.f, c3 = 0.f;
    #pragma unroll
    for (int r = 0; r < RANK; ++r) {
        const float ar = (r < 4  ? (&a0.x)[r]
                        : r < 8  ? (&a1.x)[r - 4]
                        : r < 12 ? (&a2.x)[r - 8]
                                 : (&a3.x)[r - 12]);
        const float4 br = ((const float4*)(Bs + r * NF))[lane];
        c0 = fmaf(ar, br.x, c0);
        c1 = fmaf(ar, br.y, c1);
        c2 = fmaf(ar, br.z, c2);
        c3 = fmaf(ar, br.w, c3);
    }

    // ---- 4. Partial dot: ue . (ie + corr)
    float p = ue.x * (ie.x + c0)
            + ue.y * (ie.y + c1)
            + ue.z * (ie.z + c2)
            + ue.w * (ie.w + c3);

    // ---- 5. Reduce across the 16-lane group.
    p += __shfl_xor(p, 8, 16);
    p += __shfl_xor(p, 4, 16);
    p += __shfl_xor(p, 2, 16);
    p += __shfl_xor(p, 1, 16);

    if (lane == 0 && i < batch) {
        out[i] = p + ub + ib;
    }
}

extern "C" void kernel_launch(void* const* d_in, const int* in_sizes, int n_in,
                              void* d_out, int out_size, void* d_ws, size_t ws_size,
                              hipStream_t stream) {
    const int*   users     = (const int*)  d_in[0];
    const int*   items     = (const int*)  d_in[1];
    const float* user_emb  = (const float*)d_in[2];
    const float* item_emb  = (const float*)d_in[3];
    const float* user_bias = (const float*)d_in[4];
    const float* item_bias = (const float*)d_in[5];
    const float* A         = (const float*)d_in[6];
    const float* Bm        = (const float*)d_in[7];
    float* out = (float*)d_out;

    const int batch = in_sizes[0];             // 16384
    const int groups_per_block = 16;           // 256 threads / 16 lanes
    const int grid = (batch + groups_per_block - 1) / groups_per_block;  // 1024

    MF_27436251087258_kernel<<<grid, 256, 0, stream>>>(
        users, items, user_emb, item_emb, user_bias, item_bias, A, Bm, out, batch);
}

// Round 6
// 9.782 us; speedup vs baseline: 1.2544x; 1.0089x over previous
//
#include <hip/hip_runtime.h>

#define NF 64
#define RANK 16
// Single-wave blocks: 64 threads = 1 wave = 4 outputs (16-lane groups).
// 4096 blocks for BATCH=16384. No inter-wave coupling: the __syncthreads()
// is wave-internal (no cross-wave max-of-gather-latency stall). Each wave
// stages B (4 KB, L2-hot after first touch) into its own LDS copy.

__global__ __launch_bounds__(64) void MF_27436251087258_kernel(
    const int* __restrict__ users,
    const int* __restrict__ items,
    const float* __restrict__ user_emb,
    const float* __restrict__ item_emb,
    const float* __restrict__ user_bias,
    const float* __restrict__ item_bias,
    const float* __restrict__ A,
    const float* __restrict__ Bm,
    float* __restrict__ out,
    int batch)
{
    __shared__ float Bs[RANK * NF];   // 4 KB per (single-wave) block

    const int tid   = threadIdx.x;    // 0..63
    const int group = tid >> 4;       // 4 groups of 16 lanes
    const int lane  = tid & 15;
    const int i = blockIdx.x * 4 + group;

    // ---- 1. Head of the dependent chain: index loads first.
    const int u  = users[i];
    const int it = items[i];

    // ---- 2. Independent B-staging loads (4 KB / 64 lanes = 4 float4 each).
    float4 b0 = ((const float4*)Bm)[0 * 64 + tid];
    float4 b1 = ((const float4*)Bm)[1 * 64 + tid];
    float4 b2 = ((const float4*)Bm)[2 * 64 + tid];
    float4 b3 = ((const float4*)Bm)[3 * 64 + tid];

    // ---- 3. All random lines issued as soon as indices arrive.
    const float ub = user_bias[u];
    const float ib = item_bias[it];
    const float4 ue = *(const float4*)(user_emb + (size_t)u  * NF + lane * 4);
    const float4 ie = *(const float4*)(item_emb + (size_t)it * NF + lane * 4);

    const float* Arow = A + (size_t)it * RANK;   // 64 B, one cache line
    const float4 a0 = *(const float4*)(Arow + 0);
    const float4 a1 = *(const float4*)(Arow + 4);
    const float4 a2 = *(const float4*)(Arow + 8);
    const float4 a3 = *(const float4*)(Arow + 12);

    // ---- 4. Write B to LDS; wave-internal barrier orders write->read.
    ((float4*)Bs)[0 * 64 + tid] = b0;
    ((float4*)Bs)[1 * 64 + tid] = b1;
    ((float4*)Bs)[2 * 64 + tid] = b2;
    ((float4*)Bs)[3 * 64 + tid] = b3;
    __syncthreads();

    // ---- 5. Low-rank correction: 16 x (ds_read_b128 + 4 FMA).
    float c0 = 0.f, c1 = 0.f, c2 = 0.f, c3 = 0.f;
    #pragma unroll
    for (int r = 0; r < RANK; ++r) {
        const float ar = (r < 4  ? (&a0.x)[r]
                        : r < 8  ? (&a1.x)[r - 4]
                        : r < 12 ? (&a2.x)[r - 8]
                                 : (&a3.x)[r - 12]);
        const float4 br = ((const float4*)(Bs + r * NF))[lane];
        c0 = fmaf(ar, br.x, c0);
        c1 = fmaf(ar, br.y, c1);
        c2 = fmaf(ar, br.z, c2);
        c3 = fmaf(ar, br.w, c3);
    }

    // ---- 6. Partial dot: ue . (ie + corr)
    float p = ue.x * (ie.x + c0)
            + ue.y * (ie.y + c1)
            + ue.z * (ie.z + c2)
            + ue.w * (ie.w + c3);

    // ---- 7. Reduce across the 16-lane group.
    p += __shfl_xor(p, 8, 16);
    p += __shfl_xor(p, 4, 16);
    p += __shfl_xor(p, 2, 16);
    p += __shfl_xor(p, 1, 16);

    if (lane == 0 && i < batch) {
        out[i] = p + ub + ib;
    }
}

extern "C" void kernel_launch(void* const* d_in, const int* in_sizes, int n_in,
                              void* d_out, int out_size, void* d_ws, size_t ws_size,
                              hipStream_t stream) {
    const int*   users     = (const int*)  d_in[0];
    const int*   items     = (const int*)  d_in[1];
    const float* user_emb  = (const float*)d_in[2];
    const float* item_emb  = (const float*)d_in[3];
    const float* user_bias = (const float*)d_in[4];
    const float* item_bias = (const float*)d_in[5];
    const float* A         = (const float*)d_in[6];
    const float* Bm        = (const float*)d_in[7];
    float* out = (float*)d_out;

    const int batch = in_sizes[0];                 // 16384
    const int outputs_per_block = 4;               // one wave, 4 groups
    const int grid = (batch + outputs_per_block - 1) / outputs_per_block;  // 4096

    MF_27436251087258_kernel<<<grid, 64, 0, stream>>>(
        users, items, user_emb, item_emb, user_bias, item_bias, A, Bm, out, batch);
}